// Round 9
// baseline (3716.420 us; speedup 1.0000x reference)
//
#include <hip/hip_runtime.h>

#define NF 64
#define NH 32
#define NK 16
#define NNODES 15
#define BLOCK 512
#define SPB (BLOCK * 2)          // samples per block = 1024 (2 per thread)
#define NWAVES (BLOCK / 64)

// ILP=2: each thread carries TWO sorted-adjacent samples with fully
// interleaved, independent FMA/load chains — hides ALU + memory latency that
// R8's 27% VALUBusy showed occupancy alone can't. subset_idx staged in LDS
// (kills the per-level si->xs serial global chain). Live set ~120 floats;
// R8 demonstrated the allocator follows the live set (100 VGPR, no spill),
// so expect ~128-160 VGPR. Spill tell = WRITE_SIZE >> 2 MB.

__global__ __attribute__((amdgpu_flat_work_group_size(BLOCK, BLOCK)))
void tree_mlp_kernel(
    const float* __restrict__ x,
    const float* __restrict__ W1, const float* __restrict__ b1,
    const float* __restrict__ W2, const float* __restrict__ b2,
    const float* __restrict__ W3, const float* __restrict__ b3,
    const float* __restrict__ leaf_best, const int* __restrict__ subset_idx,
    float* __restrict__ out, int N)
{
    __shared__ unsigned permL[SPB];          // 4096 B
    __shared__ int      sortL[8 * NWAVES];   // 256 B (nb*NWAVES <= 64)
    __shared__ int      subL[NNODES * NK];   // 960 B

    const int tid  = threadIdx.x;
    const int lane = tid & 63;
    const int wv   = tid >> 6;

    for (int i = tid; i < NNODES * NK; i += BLOCK) subL[i] = subset_idx[i];
    __syncthreads();

    const int base = blockIdx.x * SPB;
    const int sa = base + 2 * tid;
    const int sb = sa + 1;
    int valid_a = (sa < N) ? 1 : 0,  valid_b = (sb < N) ? 1 : 0;
    int id_a = valid_a ? sa : 0,     id_b = valid_b ? sb : 0;
    int loc_a = 0, loc_b = 0, off = 0;

    const unsigned long long below   = (1ull << lane) - 1ull;
    const unsigned long long beloweq = below | (1ull << lane);

    #pragma unroll 1                 // keep level loop rolled (I$; body ~3.5k FMAs)
    for (int level = 0; level < 4; ++level) {
        if (level > 0) {
            // ---- in-block counting sort of 1024 elements by loc ----
            const int nb = 1 << level;
            int rank_a = 0, rank_b = 0;
            #pragma unroll 1
            for (int b = 0; b < nb; ++b) {
                const unsigned long long ma = __ballot(loc_a == b);
                const unsigned long long mb = __ballot(loc_b == b);
                if (loc_a == b) rank_a = __popcll(ma & below) + __popcll(mb & below);
                if (loc_b == b) rank_b = __popcll(ma & beloweq) + __popcll(mb & below);
                if (lane == 0)
                    sortL[b * NWAVES + wv] = (int)(__popcll(ma) + __popcll(mb));
            }
            __syncthreads();
            if (wv == 0) {           // wave-parallel exclusive prefix (<=64 entries)
                const int mcnt = nb * NWAVES;
                const int cnt = (lane < mcnt) ? sortL[lane] : 0;
                int v = cnt;
                #pragma unroll
                for (int d = 1; d < 64; d <<= 1) {
                    const int t = __shfl_up(v, d);
                    if (lane >= d) v += t;
                }
                if (lane < mcnt) sortL[lane] = v - cnt;
            }
            __syncthreads();
            const int slot_a = sortL[loc_a * NWAVES + wv] + rank_a;
            const int slot_b = sortL[loc_b * NWAVES + wv] + rank_b;
            permL[slot_a] = ((unsigned)id_a << 5) | ((unsigned)valid_a << 4) | (unsigned)loc_a;
            permL[slot_b] = ((unsigned)id_b << 5) | ((unsigned)valid_b << 4) | (unsigned)loc_b;
            __syncthreads();
            const unsigned pa = permL[2 * tid];
            const unsigned pb = permL[2 * tid + 1];
            id_a = (int)(pa >> 5); valid_a = (int)((pa >> 4) & 1u); loc_a = (int)(pa & 15u);
            id_b = (int)(pb >> 5); valid_b = (int)((pb >> 4) & 1u); loc_b = (int)(pb & 15u);
        }

        const int node_a = off + loc_a;      // adjacent sorted slots: nearly always equal
        const int node_b = off + loc_b;
        const float* xra = x + (size_t)id_a * NF;
        const float* xrb = x + (size_t)id_b * NF;

        // Gather 16 subset features per sample (si from LDS; both streams issue together)
        float xs_a[NK], xs_b[NK];
        const int* sia = subL + node_a * NK;
        const int* sib = subL + node_b * NK;
        #pragma unroll
        for (int k = 0; k < NK; ++k) { xs_a[k] = xra[sia[k]]; xs_b[k] = xrb[sib[k]]; }

        // h1 = leaky(W1 @ xs + b1), two interleaved independent chains
        float h1a[NH], h1b[NH];
        const float4* w1ga = (const float4*)(W1 + node_a * (NH * NK));
        const float4* w1gb = (const float4*)(W1 + node_b * (NH * NK));
        const float* b1ga = b1 + node_a * NH;
        const float* b1gb = b1 + node_b * NH;
        #pragma unroll
        for (int j = 0; j < NH; ++j) {
            float aa = b1ga[j], ab = b1gb[j];
            #pragma unroll
            for (int q = 0; q < NK / 4; ++q) {
                const float4 ta = w1ga[j * 4 + q];
                const float4 tb = w1gb[j * 4 + q];
                aa += ta.x * xs_a[q * 4 + 0]; ab += tb.x * xs_b[q * 4 + 0];
                aa += ta.y * xs_a[q * 4 + 1]; ab += tb.y * xs_b[q * 4 + 1];
                aa += ta.z * xs_a[q * 4 + 2]; ab += tb.z * xs_b[q * 4 + 2];
                aa += ta.w * xs_a[q * 4 + 3]; ab += tb.w * xs_b[q * 4 + 3];
            }
            h1a[j] = (aa >= 0.f) ? aa : 0.01f * aa;
            h1b[j] = (ab >= 0.f) ? ab : 0.01f * ab;
        }

        // h2 + logits fused (h2 dies at birth), two interleaved chains
        const float4* w2ga = (const float4*)(W2 + node_a * (NH * NH));
        const float4* w2gb = (const float4*)(W2 + node_b * (NH * NH));
        const float* b2ga = b2 + node_a * NH;
        const float* b2gb = b2 + node_b * NH;
        const float* w3ga = W3 + node_a * 2 * NH;
        const float* w3gb = W3 + node_b * 2 * NH;
        float l0a = b3[node_a * 2 + 0], l1a = b3[node_a * 2 + 1];
        float l0b = b3[node_b * 2 + 0], l1b = b3[node_b * 2 + 1];
        #pragma unroll
        for (int g = 0; g < NH; ++g) {
            float aa = b2ga[g], ab = b2gb[g];
            #pragma unroll
            for (int q = 0; q < NH / 4; ++q) {
                const float4 ta = w2ga[g * 8 + q];
                const float4 tb = w2gb[g * 8 + q];
                aa += ta.x * h1a[q * 4 + 0]; ab += tb.x * h1b[q * 4 + 0];
                aa += ta.y * h1a[q * 4 + 1]; ab += tb.y * h1b[q * 4 + 1];
                aa += ta.z * h1a[q * 4 + 2]; ab += tb.z * h1b[q * 4 + 2];
                aa += ta.w * h1a[q * 4 + 3]; ab += tb.w * h1b[q * 4 + 3];
            }
            const float h2a = (aa >= 0.f) ? aa : 0.01f * aa;
            const float h2b = (ab >= 0.f) ? ab : 0.01f * ab;
            l0a += w3ga[g]      * h2a;  l0b += w3gb[g]      * h2b;
            l1a += w3ga[NH + g] * h2a;  l1b += w3gb[NH + g] * h2b;
        }

        // p0 < 0.5  <=>  l0 < l1  (softmax is monotone)
        loc_a = 2 * loc_a + ((l0a < l1a) ? 1 : 0);
        loc_b = 2 * loc_b + ((l0b < l1b) ? 1 : 0);
        off = 2 * off + 1;               // node offsets: 0, 1, 3, 7
    }

    if (valid_a) out[id_a] = leaf_best[loc_a];
    if (valid_b) out[id_b] = leaf_best[loc_b];
}

extern "C" void kernel_launch(void* const* d_in, const int* in_sizes, int n_in,
                              void* d_out, int out_size, void* d_ws, size_t ws_size,
                              hipStream_t stream) {
    const float* x         = (const float*)d_in[0];
    const float* W1        = (const float*)d_in[1];
    const float* b1        = (const float*)d_in[2];
    const float* W2        = (const float*)d_in[3];
    const float* b2        = (const float*)d_in[4];
    const float* W3        = (const float*)d_in[5];
    const float* b3        = (const float*)d_in[6];
    const float* leaf_best = (const float*)d_in[7];
    const int*   subset    = (const int*)d_in[8];

    const int N = in_sizes[0] / NF;
    const int grid = (N + SPB - 1) / SPB;
    tree_mlp_kernel<<<grid, BLOCK, 0, stream>>>(
        x, W1, b1, W2, b2, W3, b3, leaf_best, subset, (float*)d_out, N);
}